// Round 8
// baseline (371.016 us; speedup 1.0000x reference)
//
#include <hip/hip_runtime.h>
#include <stdint.h>

#define FEAT 128
#define ECH 2048   // edges per econv block
#define CAP 200000 // per-partition edge capacity (E/4, generous vs E/8 expected)

typedef short bf16x8 __attribute__((ext_vector_type(8)));
typedef unsigned short u16x8 __attribute__((ext_vector_type(8)));
typedef float f32x4 __attribute__((ext_vector_type(4)));

__device__ __forceinline__ float bflo(uint32_t u) {
    uint32_t t = u << 16;
    return __builtin_bit_cast(float, t);
}
__device__ __forceinline__ float bfhi(uint32_t u) {
    uint32_t t = u & 0xffff0000u;
    return __builtin_bit_cast(float, t);
}
__device__ __forceinline__ float bfs(unsigned short u) {
    uint32_t t = ((uint32_t)u) << 16;
    return __builtin_bit_cast(float, t);
}
__device__ __forceinline__ unsigned short f2bf(float f) {
    uint32_t u = __builtin_bit_cast(uint32_t, f);
    u += 0x7fffu + ((u >> 16) & 1u);
    return (unsigned short)(u >> 16);
}

// ---- edge decode + layout-detect + bucket by dst partition --------------
// Inline detect: int64 edges (<n) have zero odd words; int32 has random ids.
__launch_bounds__(256)
__global__ void k_econv(const int* __restrict__ ei, int2* __restrict__ ebuf,
                        int* __restrict__ bcnt, int E, int n, int psz) {
    __shared__ int lflag;
    __shared__ int cnt[8], lofs[8], gbase[8];
    __shared__ int2 stage[ECH];
    __shared__ char sb[ECH];
    int t = threadIdx.x;
    if (t == 0) lflag = 0;
    if (t < 8) cnt[t] = 0;
    __syncthreads();
    if (ei[1 + 2 * t] != 0) atomicOr(&lflag, 1);   // odd words 1..511
    __syncthreads();
    int is32 = lflag;

    int base = blockIdx.x * ECH;
    int s[8], d[8], p[8], slot[8];
    #pragma unroll
    for (int j = 0; j < 8; j++) {
        int e = base + j * 256 + t;
        int ss = 0, dd = 0;
        if (e < E) {
            ss = is32 ? ei[e]     : ei[2 * e];
            dd = is32 ? ei[E + e] : ei[2 * E + 2 * e];
            if ((unsigned)ss >= (unsigned)n) ss = 0;
            if ((unsigned)dd >= (unsigned)n) dd = 0;
            int pp = dd / psz;
            if (pp > 7) pp = 7;
            p[j] = pp;
            slot[j] = atomicAdd(&cnt[pp], 1);
        } else p[j] = -1;
        s[j] = ss; d[j] = dd;
    }
    __syncthreads();
    if (t == 0) {
        int acc = 0;
        #pragma unroll
        for (int i = 0; i < 8; i++) { lofs[i] = acc; acc += cnt[i]; }
    }
    __syncthreads();
    if (t < 8) gbase[t] = atomicAdd(&bcnt[t], cnt[t]);
    __syncthreads();
    #pragma unroll
    for (int j = 0; j < 8; j++) {
        if (p[j] >= 0) {
            int pos = lofs[p[j]] + slot[j];
            stage[pos] = make_int2(s[j], d[j]);
            sb[pos] = (char)p[j];
        }
    }
    __syncthreads();
    int tot = lofs[7] + cnt[7];
    for (int i = t; i < tot; i += 256) {
        int pp = sb[i];
        int off = gbase[pp] + (i - lofs[pp]);
        if (off < CAP) ebuf[(size_t)pp * CAP + off] = stage[i];
    }
}

// ---- split x (+ inline dtype sample, + zero deg) ------------------------
__launch_bounds__(256)
__global__ void k_split(const void* __restrict__ in, int m8, int n,
                        int* __restrict__ deg,
                        u16x8* __restrict__ hi, u16x8* __restrict__ lo) {
    __shared__ int hits;
    int t = threadIdx.x;
    if (t == 0) hits = 0;
    __syncthreads();
    unsigned ew = (((const uint32_t*)in)[t] >> 7) & 0xFFu;
    unsigned long long bl = __ballot(ew >= 0x60u && ew <= 0x90u);
    if ((t & 63) == 0) atomicAdd(&hits, (int)__popcll(bl));
    __syncthreads();
    int isbf = (2 * hits > 256);

    int i = blockIdx.x * 256 + t;
    if (i < n) deg[i] = 0;
    if (i >= m8) return;
    if (isbf) {
        hi[i] = ((const u16x8*)in)[i];
        u16x8 z = {0,0,0,0,0,0,0,0};
        lo[i] = z;
    } else {
        const float4* f4 = (const float4*)in;
        float4 f0 = f4[2 * i], f1 = f4[2 * i + 1];
        float v[8] = {f0.x, f0.y, f0.z, f0.w, f1.x, f1.y, f1.z, f1.w};
        u16x8 h, l;
        #pragma unroll
        for (int j = 0; j < 8; j++) {
            unsigned short hh = f2bf(v[j]);
            h[j] = hh;
            l[j] = f2bf(v[j] - bfs(hh));
        }
        hi[i] = h;
        lo[i] = l;
    }
}

// ---- weight/bias prep: W1,W2 -> transposed hi/lo splits; b/Wfc/bfc -> f32
__launch_bounds__(256)
__global__ void k_wprep(const void* W1, const void* W2,
                        const void* b1, const void* b2,
                        const void* Wfc, const void* bfc,
                        unsigned short* Wth1, unsigned short* Wtl1,
                        unsigned short* Wth2, unsigned short* Wtl2,
                        float* b1f, float* b2f, float* Wfcf, float* bfcf) {
    __shared__ int hits;
    int blk = blockIdx.x, t = threadIdx.x;
    const uint32_t* samp = (const uint32_t*)(blk < 64 ? W1 : (blk < 128 ? W2 : Wfc));
    if (t == 0) hits = 0;
    __syncthreads();
    unsigned ew = (samp[t] >> 7) & 0xFFu;
    unsigned long long bl = __ballot(ew >= 0x60u && ew <= 0x90u);
    if ((t & 63) == 0) atomicAdd(&hits, (int)__popcll(bl));
    __syncthreads();
    int isbf = (2 * hits > 256);

    if (blk < 128) {
        const void* W = (blk < 64) ? W1 : W2;
        unsigned short* th = (blk < 64) ? Wth1 : Wth2;
        unsigned short* tl = (blk < 64) ? Wtl1 : Wtl2;
        int idx = (blk & 63) * 256 + t;       // 0..16383
        int nn = idx >> 7, k = idx & 127;
        int si = k * 128 + nn;
        float f = isbf ? bfs(((const unsigned short*)W)[si])
                       : ((const float*)W)[si];
        unsigned short h = f2bf(f);
        th[nn * 128 + k] = h;
        tl[nn * 128 + k] = f2bf(f - bfs(h));
    } else {
        int i = (blk - 128) * 256 + t;        // 0..4607 (need 4384)
        if (i >= 4384) return;
        const void* src; float* dst; int off;
        if (i < 128)       { src = b1;  dst = b1f;  off = i; }
        else if (i < 256)  { src = b2;  dst = b2f;  off = i - 128; }
        else if (i < 4352) { src = Wfc; dst = Wfcf; off = i - 256; }
        else               { src = bfc; dst = bfcf; off = i - 4352; }
        dst[off] = isbf ? bfs(((const unsigned short*)src)[off])
                        : ((const float*)src)[off];
    }
}

// ---- partitioned degree count (bucketed edges, single pass) -------------
__launch_bounds__(256)
__global__ void k_degp(const int2* __restrict__ ebuf, const int* __restrict__ bcnt,
                       int* __restrict__ deg) {
    int p = blockIdx.x & 7;
    int nb = gridDim.x >> 3;
    int cnt = bcnt[p]; if (cnt > CAP) cnt = CAP;
    const int2* eb = ebuf + (size_t)p * CAP;
    for (int i = (blockIdx.x >> 3) * 256 + threadIdx.x; i < cnt; i += nb * 256)
        atomicAdd(&deg[eb[i].y], 1);
}

// ---- fused scan (decoupled lookback): deg -> row_ptr/cursor/dinv --------
__launch_bounds__(256)
__global__ void k_scan3(const int* __restrict__ deg, float* __restrict__ dinv,
                        int* __restrict__ row_ptr, int* __restrict__ cursor,
                        long long* __restrict__ lb, int n) {
    __shared__ int wsum[4];
    __shared__ int exc;
    int b = blockIdx.x, t = threadIdx.x, lane = t & 63, w = t >> 6;
    int idx = b * 256 + t;
    int v = (idx < n) ? deg[idx] : 0;
    if (idx < n) dinv[idx] = rsqrtf((float)(v + 1));  // +1 self-loop
    int s = v;
    #pragma unroll
    for (int off = 1; off < 64; off <<= 1) {
        int x = __shfl_up(s, off, 64);
        if (lane >= off) s += x;
    }
    if (lane == 63) wsum[w] = s;
    __syncthreads();
    if (t == 0) {
        int acc = 0;
        #pragma unroll
        for (int i = 0; i < 4; i++) { int x = wsum[i]; wsum[i] = acc; acc += x; }
        int total = acc;
        __hip_atomic_store(&lb[b], ((long long)total << 2) | 1,
                           __ATOMIC_RELEASE, __HIP_MEMORY_SCOPE_AGENT);
        long long run = 0;
        for (int j = b - 1; j >= 0; ) {
            long long x = __hip_atomic_load(&lb[j], __ATOMIC_ACQUIRE,
                                            __HIP_MEMORY_SCOPE_AGENT);
            int st = (int)(x & 3);
            if (st == 0) continue;   // spin until predecessor publishes
            run += (x >> 2);
            if (st == 2) break;      // inclusive prefix found
            j--;
        }
        __hip_atomic_store(&lb[b], (((long long)total + run) << 2) | 2,
                           __ATOMIC_RELEASE, __HIP_MEMORY_SCOPE_AGENT);
        exc = (int)run;
    }
    __syncthreads();
    int ex = exc + s - v + wsum[w];
    if (idx < n) { row_ptr[idx] = ex; cursor[idx] = ex; }
    if (idx == n - 1) row_ptr[n] = ex + v;
}

// ---- partitioned scatter (bucketed edges, single pass) ------------------
__launch_bounds__(256)
__global__ void k_scatp(const int2* __restrict__ ebuf, const int* __restrict__ bcnt,
                        int* __restrict__ cursor, int* __restrict__ col, int E) {
    int p = blockIdx.x & 7;
    int nb = gridDim.x >> 3;
    int cnt = bcnt[p]; if (cnt > CAP) cnt = CAP;
    const int2* eb = ebuf + (size_t)p * CAP;
    for (int i = (blockIdx.x >> 3) * 256 + threadIdx.x; i < cnt; i += nb * 256) {
        int2 e = eb[i];
        int pos = atomicAdd(&cursor[e.y], 1);
        if ((unsigned)pos < (unsigned)E) col[pos] = e.x;
    }
}

// ---- GEMM: hs_bf16 = dinv[row] * (X @ W), split-bf16 MFMA ---------------
__launch_bounds__(64)
__global__ void k_gemm(const unsigned short* __restrict__ Xh,
                       const unsigned short* __restrict__ Xl,
                       const unsigned short* __restrict__ Wth,
                       const unsigned short* __restrict__ Wtl,
                       const float* __restrict__ dinv,
                       unsigned short* __restrict__ hs, int n, int use_xlo) {
    int l = threadIdx.x;
    int quad = l >> 4;
    int m16 = l & 15;
    int r0 = blockIdx.x * 16;

    int ra = r0 + m16;
    if (ra > n - 1) ra = n - 1;
    const int4* Xvh = (const int4*)Xh;
    const int4* Xvl = (const int4*)Xl;
    bf16x8 ah[4], al[4];
    #pragma unroll
    for (int kt = 0; kt < 4; kt++)
        ah[kt] = __builtin_bit_cast(bf16x8, Xvh[ra * 16 + kt * 4 + quad]);
    if (use_xlo) {
        #pragma unroll
        for (int kt = 0; kt < 4; kt++)
            al[kt] = __builtin_bit_cast(bf16x8, Xvl[ra * 16 + kt * 4 + quad]);
    }

    float dv[4];
    #pragma unroll
    for (int reg = 0; reg < 4; reg++) {
        int row = r0 + quad * 4 + reg;
        if (row > n - 1) row = n - 1;
        dv[reg] = dinv[row];
    }

    const int4* Wvh = (const int4*)Wth;
    const int4* Wvl = (const int4*)Wtl;
    #pragma unroll
    for (int nt = 0; nt < 8; nt++) {
        f32x4 acc = {0.f, 0.f, 0.f, 0.f};
        int brow = (nt * 16 + m16) * 16;
        #pragma unroll
        for (int kt = 0; kt < 4; kt++) {
            bf16x8 bh = __builtin_bit_cast(bf16x8, Wvh[brow + kt * 4 + quad]);
            bf16x8 bl = __builtin_bit_cast(bf16x8, Wvl[brow + kt * 4 + quad]);
            acc = __builtin_amdgcn_mfma_f32_16x16x32_bf16(ah[kt], bh, acc, 0, 0, 0);
            acc = __builtin_amdgcn_mfma_f32_16x16x32_bf16(ah[kt], bl, acc, 0, 0, 0);
            if (use_xlo)
                acc = __builtin_amdgcn_mfma_f32_16x16x32_bf16(al[kt], bh, acc, 0, 0, 0);
        }
        #pragma unroll
        for (int reg = 0; reg < 4; reg++) {
            int row = r0 + quad * 4 + reg;
            if (row < n)
                hs[row * 128 + nt * 16 + m16] = f2bf(acc[reg] * dv[reg]);
        }
    }
}

// ---- Pull aggregation: act = relu(dinv*(hs[d]+sum hs[s]) + b) -----------
__launch_bounds__(256)
__global__ void k_agg(const uint32_t* __restrict__ hsv, const int* __restrict__ row_ptr,
                      const int* __restrict__ col, const float* __restrict__ dinv,
                      const float* __restrict__ bias,
                      uint32_t* __restrict__ outh, float* __restrict__ partial,
                      int n, int E) {
    __shared__ float pl[4][128];
    int wave = threadIdx.x >> 6;
    int lane = threadIdx.x & 63;
    int node = blockIdx.x * 4 + wave;
    bool active = (node < n);
    int nd = active ? node : 0;

    uint32_t su = hsv[nd * 64 + lane];
    float a0 = bflo(su), a1 = bfhi(su);

    int e = row_ptr[nd];
    int end = active ? row_ptr[nd + 1] : e;
    if (e < 0) e = 0;
    if (end > E) end = E;

    for (; e + 8 <= end; e += 8) {
        unsigned s0 = (unsigned)col[e],     s1 = (unsigned)col[e + 1];
        unsigned s2 = (unsigned)col[e + 2], s3 = (unsigned)col[e + 3];
        unsigned s4 = (unsigned)col[e + 4], s5 = (unsigned)col[e + 5];
        unsigned s6 = (unsigned)col[e + 6], s7 = (unsigned)col[e + 7];
        if (s0 >= (unsigned)n) s0 = 0;
        if (s1 >= (unsigned)n) s1 = 0;
        if (s2 >= (unsigned)n) s2 = 0;
        if (s3 >= (unsigned)n) s3 = 0;
        if (s4 >= (unsigned)n) s4 = 0;
        if (s5 >= (unsigned)n) s5 = 0;
        if (s6 >= (unsigned)n) s6 = 0;
        if (s7 >= (unsigned)n) s7 = 0;
        uint32_t u0 = hsv[s0 * 64 + lane];
        uint32_t u1 = hsv[s1 * 64 + lane];
        uint32_t u2 = hsv[s2 * 64 + lane];
        uint32_t u3 = hsv[s3 * 64 + lane];
        uint32_t u4 = hsv[s4 * 64 + lane];
        uint32_t u5 = hsv[s5 * 64 + lane];
        uint32_t u6 = hsv[s6 * 64 + lane];
        uint32_t u7 = hsv[s7 * 64 + lane];
        a0 += bflo(u0) + bflo(u1) + bflo(u2) + bflo(u3)
            + bflo(u4) + bflo(u5) + bflo(u6) + bflo(u7);
        a1 += bfhi(u0) + bfhi(u1) + bfhi(u2) + bfhi(u3)
            + bfhi(u4) + bfhi(u5) + bfhi(u6) + bfhi(u7);
    }
    for (; e < end; ++e) {
        unsigned s0 = (unsigned)col[e];
        if (s0 >= (unsigned)n) s0 = 0;
        uint32_t u = hsv[s0 * 64 + lane];
        a0 += bflo(u);
        a1 += bfhi(u);
    }

    float dv = dinv[nd];
    float2 bu = ((const float2*)bias)[lane];
    float r0 = fmaxf(dv * a0 + bu.x, 0.f);
    float r1 = fmaxf(dv * a1 + bu.y, 0.f);
    if (!active) { r0 = 0.f; r1 = 0.f; }

    if (outh != nullptr && active) {
        outh[node * 64 + lane] = (uint32_t)f2bf(r0) | ((uint32_t)f2bf(r1) << 16);
    }
    if (partial != nullptr) {
        pl[wave][2 * lane]     = r0;
        pl[wave][2 * lane + 1] = r1;
        __syncthreads();
        int t = threadIdx.x;
        if (t < 128) {
            float ps = pl[0][t] + pl[1][t] + pl[2][t] + pl[3][t];
            partial[blockIdx.x * 128 + t] = ps;
        }
    }
}

// ---- fused pooled reduce + FC (last-block pattern) ----------------------
__launch_bounds__(256)
__global__ void k_redfinal(const float* __restrict__ partial, float* __restrict__ pooled,
                           int* __restrict__ done,
                           const float* __restrict__ Wfcf, const float* __restrict__ bfcf,
                           const void* __restrict__ x, void* __restrict__ out,
                           int n, int nbrows, int gblocks) {
    __shared__ float red[8][128];
    int t = threadIdx.x;
    int chunk = (nbrows + gblocks - 1) / gblocks;
    int r0 = blockIdx.x * chunk;
    int r1 = r0 + chunk;
    if (r1 > nbrows) r1 = nbrows;

    float4 acc = {0.f, 0.f, 0.f, 0.f};
    const float4* p4 = (const float4*)partial;
    for (int i = r0 * 32 + t; i < r1 * 32; i += 256) {
        float4 v = p4[i];
        acc.x += v.x; acc.y += v.y; acc.z += v.z; acc.w += v.w;
    }
    int g = t >> 5;
    int fb = (t & 31) * 4;
    red[g][fb]     = acc.x;
    red[g][fb + 1] = acc.y;
    red[g][fb + 2] = acc.z;
    red[g][fb + 3] = acc.w;
    __syncthreads();
    if (t < 128) {
        float s = red[0][t] + red[1][t] + red[2][t] + red[3][t]
                + red[4][t] + red[5][t] + red[6][t] + red[7][t];
        atomicAdd(&pooled[t], s);
    }
    __threadfence();
    __shared__ int lastf;
    if (t == 0) lastf = (atomicAdd(done, 1) == gblocks - 1) ? 1 : 0;
    __syncthreads();
    if (!lastf) return;

    // last block: FC epilogue (+ inline x-dtype sample for output format)
    __shared__ int hits;
    __shared__ float pv[128];
    if (t == 0) hits = 0;
    __syncthreads();
    unsigned ew = (((const uint32_t*)x)[t] >> 7) & 0xFFu;
    unsigned long long bl = __ballot(ew >= 0x60u && ew <= 0x90u);
    if ((t & 63) == 0) atomicAdd(&hits, (int)__popcll(bl));
    if (t < 128)
        pv[t] = __hip_atomic_load(&pooled[t], __ATOMIC_RELAXED,
                                  __HIP_MEMORY_SCOPE_AGENT);
    __syncthreads();
    int isbf = (2 * hits > 256);
    if (t < 32) {
        float s = 0.f;
        for (int c = 0; c < 128; ++c) s += pv[c] * Wfcf[c * 32 + t];
        s = s * (1.0f / (float)n) + bfcf[t];
        if (isbf) ((unsigned short*)out)[t] = f2bf(s);
        else      ((float*)out)[t] = s;
    }
}

// ---- Launch -------------------------------------------------------------

extern "C" void kernel_launch(void* const* d_in, const int* in_sizes, int n_in,
                              void* d_out, int out_size, void* d_ws, size_t ws_size,
                              hipStream_t stream) {
    const void* x   = d_in[0];
    const int*  ei  = (const int*)d_in[1];
    const void* W1  = d_in[2];
    const void* b1  = d_in[3];
    const void* W2  = d_in[4];
    const void* b2  = d_in[5];
    const void* Wfc = d_in[6];
    const void* bfc = d_in[7];

    const int n = in_sizes[0] / FEAT;    // 50000
    const int E = in_sizes[1] / 2;       // 800000
    const int m = n * FEAT;              // 6.4M
    const int nagg = (n + 3) / 4;        // 12500
    const int psz  = (n + 7) / 8;        // 6250
    const int nscan = (n + 255) / 256;   // 196

    char* ws = (char*)d_ws;
    unsigned short* hs      = (unsigned short*)(ws);               // 12,800,000
    unsigned short* xh      = (unsigned short*)(ws + 12800000);    // 12,800,000 (x hi / act1)
    unsigned short* xl      = (unsigned short*)(ws + 25600000);    // 12,800,000 (x lo / partials)
    int*            col     = (int*)(ws + 38400000);               // 3,200,000
    int2*           ebuf    = (int2*)(ws + 41600000);              // 12,800,000 (8*CAP*8)
    int*            deg     = (int*)(ws + 54400000);               // 200,000
    int*            row_ptr = (int*)(ws + 54600000);               // 200,016
    int*            cursor  = (int*)(ws + 54800016);               // 200,000
    float*          dinv    = (float*)(ws + 55000016);             // 200,000
    unsigned short* Wth1    = (unsigned short*)(ws + 55200016);    // 32,768
    unsigned short* Wtl1    = (unsigned short*)(ws + 55232784);    // 32,768
    unsigned short* Wth2    = (unsigned short*)(ws + 55265552);    // 32,768
    unsigned short* Wtl2    = (unsigned short*)(ws + 55298320);    // 32,768
    float*          b1f     = (float*)(ws + 55331088);             // 512
    float*          b2f     = (float*)(ws + 55331600);             // 512
    float*          Wfcf    = (float*)(ws + 55332112);             // 16,384
    float*          bfcf    = (float*)(ws + 55348496);             // 128
    // small zero region (one memset): pooled | bcnt | done | pad | lb
    float*          pooled  = (float*)(ws + 55348624);             // 512
    int*            bcnt    = (int*)(ws + 55349136);               // 32
    int*            done    = (int*)(ws + 55349168);               // 4 (+12 pad)
    long long*      lb      = (long long*)(ws + 55349184);         // 196*8 = 1568

    if (ws_size < 55350752) return;  // diagnostic: zero output => ws too small

    hipMemsetAsync(pooled, 0, 512 + 32 + 16 + 1568, stream);

    // 1) decode+bucket edges (inline layout detect)
    k_econv<<<(E + ECH - 1) / ECH, 256, 0, stream>>>(ei, ebuf, bcnt, E, n, psz);
    // 2) split x (inline dtype detect) + zero deg
    k_split<<<(m / 8 + 255) / 256, 256, 0, stream>>>(x, m / 8, n, deg,
                                                     (u16x8*)xh, (u16x8*)xl);
    // 3) degree count (XCD-partitioned, single pass over bucketed edges)
    k_degp<<<512, 256, 0, stream>>>(ebuf, bcnt, deg);
    // 4) fused scan -> row_ptr/cursor/dinv
    k_scan3<<<nscan, 256, 0, stream>>>(deg, dinv, row_ptr, cursor, lb, n);
    // 5) scatter -> col (XCD-partitioned, single pass)
    k_scatp<<<512, 256, 0, stream>>>(ebuf, bcnt, cursor, col, E);
    // 6) weight prep (both layers + FC tensors, inline dtype detect)
    k_wprep<<<146, 256, 0, stream>>>(W1, W2, b1, b2, Wfc, bfc,
                                     Wth1, Wtl1, Wth2, Wtl2,
                                     b1f, b2f, Wfcf, bfcf);

    int gemm_grid = (n + 15) / 16;
    // layer 1
    k_gemm<<<gemm_grid, 64, 0, stream>>>(xh, xl, Wth1, Wtl1, dinv, hs, n, 1);
    k_agg<<<nagg, 256, 0, stream>>>((const uint32_t*)hs, row_ptr, col, dinv, b1f,
                                    (uint32_t*)xh, nullptr, n, E);
    // layer 2 (act1 in xh; partials into xl region)
    float* partial = (float*)xl;
    k_gemm<<<gemm_grid, 64, 0, stream>>>(xh, nullptr, Wth2, Wtl2, dinv, hs, n, 0);
    k_agg<<<nagg, 256, 0, stream>>>((const uint32_t*)hs, row_ptr, col, dinv, b2f,
                                    nullptr, partial, n, E);
    // fused pooled-reduce + FC
    k_redfinal<<<100, 256, 0, stream>>>(partial, pooled, done, Wfcf, bfcf,
                                        x, d_out, n, nagg, 100);
}

// Round 9
// 328.698 us; speedup vs baseline: 1.1287x; 1.1287x over previous
//
#include <hip/hip_runtime.h>
#include <stdint.h>

#define FEAT 128
#define ECH 2048   // edges per econv block
#define CAP 200000 // per-partition edge capacity

typedef short bf16x8 __attribute__((ext_vector_type(8)));
typedef unsigned short u16x8 __attribute__((ext_vector_type(8)));
typedef float f32x4 __attribute__((ext_vector_type(4)));
typedef float f32x2 __attribute__((ext_vector_type(2)));

__device__ __forceinline__ float bfs(unsigned short u) {
    uint32_t t = ((uint32_t)u) << 16;
    return __builtin_bit_cast(float, t);
}
__device__ __forceinline__ unsigned short f2bf(float f) {
    uint32_t u = __builtin_bit_cast(uint32_t, f);
    u += 0x7fffu + ((u >> 16) & 1u);
    return (unsigned short)(u >> 16);
}

// ---- edge decode + layout-detect + bucket by dst partition --------------
__launch_bounds__(256)
__global__ void k_econv(const int* __restrict__ ei, int2* __restrict__ ebuf,
                        int* __restrict__ bcnt, int E, int n, int psz) {
    __shared__ int lflag;
    __shared__ int cnt[8], lofs[8], gbase[8];
    __shared__ int2 stage[ECH];
    __shared__ char sb[ECH];
    int t = threadIdx.x;
    if (t == 0) lflag = 0;
    if (t < 8) cnt[t] = 0;
    __syncthreads();
    if (ei[1 + 2 * t] != 0) atomicOr(&lflag, 1);   // odd words: 0 => int64
    __syncthreads();
    int is32 = lflag;

    int base = blockIdx.x * ECH;
    int s[8], d[8], p[8], slot[8];
    #pragma unroll
    for (int j = 0; j < 8; j++) {
        int e = base + j * 256 + t;
        int ss = 0, dd = 0;
        if (e < E) {
            ss = is32 ? ei[e]     : ei[2 * e];
            dd = is32 ? ei[E + e] : ei[2 * E + 2 * e];
            if ((unsigned)ss >= (unsigned)n) ss = 0;
            if ((unsigned)dd >= (unsigned)n) dd = 0;
            int pp = dd / psz;
            if (pp > 7) pp = 7;
            p[j] = pp;
            slot[j] = atomicAdd(&cnt[pp], 1);
        } else p[j] = -1;
        s[j] = ss; d[j] = dd;
    }
    __syncthreads();
    if (t == 0) {
        int acc = 0;
        #pragma unroll
        for (int i = 0; i < 8; i++) { lofs[i] = acc; acc += cnt[i]; }
    }
    __syncthreads();
    if (t < 8) gbase[t] = atomicAdd(&bcnt[t], cnt[t]);
    __syncthreads();
    #pragma unroll
    for (int j = 0; j < 8; j++) {
        if (p[j] >= 0) {
            int pos = lofs[p[j]] + slot[j];
            stage[pos] = make_int2(s[j], d[j]);
            sb[pos] = (char)p[j];
        }
    }
    __syncthreads();
    int tot = lofs[7] + cnt[7];
    for (int i = t; i < tot; i += 256) {
        int pp = sb[i];
        int off = gbase[pp] + (i - lofs[pp]);
        if (off < CAP) ebuf[(size_t)pp * CAP + off] = stage[i];
    }
}

// ---- split x (+ inline dtype sample, + zero deg) ------------------------
__launch_bounds__(256)
__global__ void k_split(const void* __restrict__ in, int m8, int n,
                        int* __restrict__ deg,
                        u16x8* __restrict__ hi, u16x8* __restrict__ lo) {
    __shared__ int hits;
    int t = threadIdx.x;
    if (t == 0) hits = 0;
    __syncthreads();
    unsigned ew = (((const uint32_t*)in)[t] >> 7) & 0xFFu;
    unsigned long long bl = __ballot(ew >= 0x60u && ew <= 0x90u);
    if ((t & 63) == 0) atomicAdd(&hits, (int)__popcll(bl));
    __syncthreads();
    int isbf = (2 * hits > 256);

    int i = blockIdx.x * 256 + t;
    if (i < n) deg[i] = 0;
    if (i >= m8) return;
    if (isbf) {
        hi[i] = ((const u16x8*)in)[i];
        u16x8 z = {0,0,0,0,0,0,0,0};
        lo[i] = z;
    } else {
        const float4* f4 = (const float4*)in;
        float4 f0 = f4[2 * i], f1 = f4[2 * i + 1];
        float v[8] = {f0.x, f0.y, f0.z, f0.w, f1.x, f1.y, f1.z, f1.w};
        u16x8 h, l;
        #pragma unroll
        for (int j = 0; j < 8; j++) {
            unsigned short hh = f2bf(v[j]);
            h[j] = hh;
            l[j] = f2bf(v[j] - bfs(hh));
        }
        hi[i] = h;
        lo[i] = l;
    }
}

// ---- weight/bias prep ---------------------------------------------------
__launch_bounds__(256)
__global__ void k_wprep(const void* W1, const void* W2,
                        const void* b1, const void* b2,
                        const void* Wfc, const void* bfc,
                        unsigned short* Wth1, unsigned short* Wtl1,
                        unsigned short* Wth2, unsigned short* Wtl2,
                        float* b1f, float* b2f, float* Wfcf, float* bfcf) {
    __shared__ int hits;
    int blk = blockIdx.x, t = threadIdx.x;
    const uint32_t* samp = (const uint32_t*)(blk < 64 ? W1 : (blk < 128 ? W2 : Wfc));
    if (t == 0) hits = 0;
    __syncthreads();
    unsigned ew = (samp[t] >> 7) & 0xFFu;
    unsigned long long bl = __ballot(ew >= 0x60u && ew <= 0x90u);
    if ((t & 63) == 0) atomicAdd(&hits, (int)__popcll(bl));
    __syncthreads();
    int isbf = (2 * hits > 256);

    if (blk < 128) {
        const void* W = (blk < 64) ? W1 : W2;
        unsigned short* th = (blk < 64) ? Wth1 : Wth2;
        unsigned short* tl = (blk < 64) ? Wtl1 : Wtl2;
        int idx = (blk & 63) * 256 + t;
        int nn = idx >> 7, k = idx & 127;
        int si = k * 128 + nn;
        float f = isbf ? bfs(((const unsigned short*)W)[si])
                       : ((const float*)W)[si];
        unsigned short h = f2bf(f);
        th[nn * 128 + k] = h;
        tl[nn * 128 + k] = f2bf(f - bfs(h));
    } else {
        int i = (blk - 128) * 256 + t;
        if (i >= 4384) return;
        const void* src; float* dst; int off;
        if (i < 128)       { src = b1;  dst = b1f;  off = i; }
        else if (i < 256)  { src = b2;  dst = b2f;  off = i - 128; }
        else if (i < 4352) { src = Wfc; dst = Wfcf; off = i - 256; }
        else               { src = bfc; dst = bfcf; off = i - 4352; }
        dst[off] = isbf ? bfs(((const unsigned short*)src)[off])
                        : ((const float*)src)[off];
    }
}

// ---- partitioned degree count (bucketed edges, single pass) -------------
__launch_bounds__(256)
__global__ void k_degp(const int2* __restrict__ ebuf, const int* __restrict__ bcnt,
                       int* __restrict__ deg) {
    int p = blockIdx.x & 7;
    int nb = gridDim.x >> 3;
    int cnt = bcnt[p]; if (cnt > CAP) cnt = CAP;
    const int2* eb = ebuf + (size_t)p * CAP;
    for (int i = (blockIdx.x >> 3) * 256 + threadIdx.x; i < cnt; i += nb * 256)
        atomicAdd(&deg[eb[i].y], 1);
}

// ---- 3-phase scan: block sums (+dinv) -> scan of sums -> apply ----------
__global__ void k_bsum(const int* __restrict__ deg, int* __restrict__ bsum,
                       float* __restrict__ dinv, int n) {
    __shared__ int ws[4];
    int t = threadIdx.x, lane = t & 63, w = t >> 6;
    int idx = blockIdx.x * 256 + t;
    int v = (idx < n) ? deg[idx] : 0;
    if (idx < n) dinv[idx] = rsqrtf((float)(v + 1));  // +1 self-loop
    int r = v;
    #pragma unroll
    for (int off = 32; off > 0; off >>= 1) r += __shfl_down(r, off, 64);
    if (lane == 0) ws[w] = r;
    __syncthreads();
    if (t == 0) bsum[blockIdx.x] = ws[0] + ws[1] + ws[2] + ws[3];
}

__global__ void k_bscan(const int* __restrict__ bsum, int* __restrict__ boff,
                        int* __restrict__ row_ptr, int nb, int n) {
    __shared__ int wsum[4];
    int t = threadIdx.x, lane = t & 63, w = t >> 6;
    int v = (t < nb) ? bsum[t] : 0;
    int s = v;
    #pragma unroll
    for (int off = 1; off < 64; off <<= 1) {
        int x = __shfl_up(s, off, 64);
        if (lane >= off) s += x;
    }
    if (lane == 63) wsum[w] = s;
    __syncthreads();
    if (t == 0) {
        int acc = 0;
        #pragma unroll
        for (int i = 0; i < 4; i++) { int x = wsum[i]; wsum[i] = acc; acc += x; }
    }
    __syncthreads();
    int excl = s - v + wsum[w];
    if (t < nb) boff[t] = excl;
    if (t == nb - 1) row_ptr[n] = excl + v;
}

__global__ void k_bapply(const int* __restrict__ deg, const int* __restrict__ boff,
                         int* __restrict__ row_ptr, int* __restrict__ cursor, int n) {
    __shared__ int wsum[4];
    int t = threadIdx.x, lane = t & 63, w = t >> 6;
    int idx = blockIdx.x * 256 + t;
    int v = (idx < n) ? deg[idx] : 0;
    int s = v;
    #pragma unroll
    for (int off = 1; off < 64; off <<= 1) {
        int x = __shfl_up(s, off, 64);
        if (lane >= off) s += x;
    }
    if (lane == 63) wsum[w] = s;
    __syncthreads();
    if (t == 0) {
        int acc = 0;
        #pragma unroll
        for (int i = 0; i < 4; i++) { int x = wsum[i]; wsum[i] = acc; acc += x; }
    }
    __syncthreads();
    int ex = boff[blockIdx.x] + s - v + wsum[w];
    if (idx < n) {
        row_ptr[idx] = ex;
        cursor[idx]  = ex;
    }
}

// ---- partitioned scatter (bucketed edges, single pass) ------------------
__launch_bounds__(256)
__global__ void k_scatp(const int2* __restrict__ ebuf, const int* __restrict__ bcnt,
                        int* __restrict__ cursor, int* __restrict__ col, int E) {
    int p = blockIdx.x & 7;
    int nb = gridDim.x >> 3;
    int cnt = bcnt[p]; if (cnt > CAP) cnt = CAP;
    const int2* eb = ebuf + (size_t)p * CAP;
    for (int i = (blockIdx.x >> 3) * 256 + threadIdx.x; i < cnt; i += nb * 256) {
        int2 e = eb[i];
        int pos = atomicAdd(&cursor[e.y], 1);
        if ((unsigned)pos < (unsigned)E) col[pos] = e.x;
    }
}

// ---- GEMM: hs_fp8 = fp8(dinv[row] * (X @ W)), split-bf16 MFMA -----------
// epilogue: fp8-pack via 2KB LDS tile -> coalesced dword stores (128 B/row)
__launch_bounds__(64)
__global__ void k_gemm(const unsigned short* __restrict__ Xh,
                       const unsigned short* __restrict__ Xl,
                       const unsigned short* __restrict__ Wth,
                       const unsigned short* __restrict__ Wtl,
                       const float* __restrict__ dinv,
                       uint32_t* __restrict__ hs8, int n, int use_xlo) {
    __shared__ unsigned char lds8[16 * 128];
    int l = threadIdx.x;
    int quad = l >> 4;
    int m16 = l & 15;
    int r0 = blockIdx.x * 16;

    int ra = r0 + m16;
    if (ra > n - 1) ra = n - 1;
    const int4* Xvh = (const int4*)Xh;
    const int4* Xvl = (const int4*)Xl;
    bf16x8 ah[4], al[4];
    #pragma unroll
    for (int kt = 0; kt < 4; kt++)
        ah[kt] = __builtin_bit_cast(bf16x8, Xvh[ra * 16 + kt * 4 + quad]);
    if (use_xlo) {
        #pragma unroll
        for (int kt = 0; kt < 4; kt++)
            al[kt] = __builtin_bit_cast(bf16x8, Xvl[ra * 16 + kt * 4 + quad]);
    }

    float dv[4];
    #pragma unroll
    for (int reg = 0; reg < 4; reg++) {
        int row = r0 + quad * 4 + reg;
        if (row > n - 1) row = n - 1;
        dv[reg] = dinv[row];
    }

    const int4* Wvh = (const int4*)Wth;
    const int4* Wvl = (const int4*)Wtl;
    #pragma unroll
    for (int nt = 0; nt < 8; nt++) {
        f32x4 acc = {0.f, 0.f, 0.f, 0.f};
        int brow = (nt * 16 + m16) * 16;
        #pragma unroll
        for (int kt = 0; kt < 4; kt++) {
            bf16x8 bh = __builtin_bit_cast(bf16x8, Wvh[brow + kt * 4 + quad]);
            bf16x8 bl = __builtin_bit_cast(bf16x8, Wvl[brow + kt * 4 + quad]);
            acc = __builtin_amdgcn_mfma_f32_16x16x32_bf16(ah[kt], bh, acc, 0, 0, 0);
            acc = __builtin_amdgcn_mfma_f32_16x16x32_bf16(ah[kt], bl, acc, 0, 0, 0);
            if (use_xlo)
                acc = __builtin_amdgcn_mfma_f32_16x16x32_bf16(al[kt], bh, acc, 0, 0, 0);
        }
        #pragma unroll
        for (int reg = 0; reg < 4; reg++) {
            float v = acc[reg] * dv[reg];
            int pk = __builtin_amdgcn_cvt_pk_fp8_f32(v, v, 0, false);
            lds8[(quad * 4 + reg) * 128 + nt * 16 + m16] = (unsigned char)(pk & 0xFF);
        }
    }
    __syncthreads();
    const uint32_t* l32 = (const uint32_t*)lds8;
    #pragma unroll
    for (int i = 0; i < 8; i++) {
        int idx = i * 64 + l;          // 0..511
        int row = idx >> 5;            // 0..15
        int grow = r0 + row;
        if (grow < n) hs8[grow * 32 + (idx & 31)] = l32[idx];
    }
}

// ---- Pull aggregation (fp8 hs): act = relu(dinv*(hs[d]+sum hs[s]) + b) --
// hs rows are 128 B fp8: lane reads ushort = features (2*lane, 2*lane+1)
__launch_bounds__(256)
__global__ void k_agg(const unsigned short* __restrict__ hsv,
                      const int* __restrict__ row_ptr,
                      const int* __restrict__ col, const float* __restrict__ dinv,
                      const float* __restrict__ bias,
                      uint32_t* __restrict__ outh, float* __restrict__ partial,
                      int n, int E) {
    __shared__ float pl[4][128];
    int wave = threadIdx.x >> 6;
    int lane = threadIdx.x & 63;
    int node = blockIdx.x * 4 + wave;
    bool active = (node < n);
    int nd = active ? node : 0;

    f32x2 sf = __builtin_amdgcn_cvt_pk_f32_fp8((int)hsv[nd * 64 + lane], false);
    float a0 = sf.x, a1 = sf.y;

    int e = row_ptr[nd];
    int end = active ? row_ptr[nd + 1] : e;
    if (e < 0) e = 0;
    if (end > E) end = E;

    for (; e + 8 <= end; e += 8) {
        unsigned s0 = (unsigned)col[e],     s1 = (unsigned)col[e + 1];
        unsigned s2 = (unsigned)col[e + 2], s3 = (unsigned)col[e + 3];
        unsigned s4 = (unsigned)col[e + 4], s5 = (unsigned)col[e + 5];
        unsigned s6 = (unsigned)col[e + 6], s7 = (unsigned)col[e + 7];
        if (s0 >= (unsigned)n) s0 = 0;
        if (s1 >= (unsigned)n) s1 = 0;
        if (s2 >= (unsigned)n) s2 = 0;
        if (s3 >= (unsigned)n) s3 = 0;
        if (s4 >= (unsigned)n) s4 = 0;
        if (s5 >= (unsigned)n) s5 = 0;
        if (s6 >= (unsigned)n) s6 = 0;
        if (s7 >= (unsigned)n) s7 = 0;
        int u0 = hsv[s0 * 64 + lane];
        int u1 = hsv[s1 * 64 + lane];
        int u2 = hsv[s2 * 64 + lane];
        int u3 = hsv[s3 * 64 + lane];
        int u4 = hsv[s4 * 64 + lane];
        int u5 = hsv[s5 * 64 + lane];
        int u6 = hsv[s6 * 64 + lane];
        int u7 = hsv[s7 * 64 + lane];
        f32x2 f0 = __builtin_amdgcn_cvt_pk_f32_fp8(u0, false);
        f32x2 f1 = __builtin_amdgcn_cvt_pk_f32_fp8(u1, false);
        f32x2 f2 = __builtin_amdgcn_cvt_pk_f32_fp8(u2, false);
        f32x2 f3 = __builtin_amdgcn_cvt_pk_f32_fp8(u3, false);
        f32x2 f4 = __builtin_amdgcn_cvt_pk_f32_fp8(u4, false);
        f32x2 f5 = __builtin_amdgcn_cvt_pk_f32_fp8(u5, false);
        f32x2 f6 = __builtin_amdgcn_cvt_pk_f32_fp8(u6, false);
        f32x2 f7 = __builtin_amdgcn_cvt_pk_f32_fp8(u7, false);
        a0 += f0.x + f1.x + f2.x + f3.x + f4.x + f5.x + f6.x + f7.x;
        a1 += f0.y + f1.y + f2.y + f3.y + f4.y + f5.y + f6.y + f7.y;
    }
    for (; e < end; ++e) {
        unsigned s0 = (unsigned)col[e];
        if (s0 >= (unsigned)n) s0 = 0;
        f32x2 f = __builtin_amdgcn_cvt_pk_f32_fp8((int)hsv[s0 * 64 + lane], false);
        a0 += f.x;
        a1 += f.y;
    }

    float dv = dinv[nd];
    float2 bu = ((const float2*)bias)[lane];
    float r0 = fmaxf(dv * a0 + bu.x, 0.f);
    float r1 = fmaxf(dv * a1 + bu.y, 0.f);
    if (!active) { r0 = 0.f; r1 = 0.f; }

    if (outh != nullptr && active) {
        outh[node * 64 + lane] = (uint32_t)f2bf(r0) | ((uint32_t)f2bf(r1) << 16);
    }
    if (partial != nullptr) {
        pl[wave][2 * lane]     = r0;
        pl[wave][2 * lane + 1] = r1;
        __syncthreads();
        int t = threadIdx.x;
        if (t < 128) {
            float ps = pl[0][t] + pl[1][t] + pl[2][t] + pl[3][t];
            partial[blockIdx.x * 128 + t] = ps;
        }
    }
}

// ---- fused pooled reduce + FC (last-block pattern) ----------------------
__launch_bounds__(256)
__global__ void k_redfinal(const float* __restrict__ partial, float* __restrict__ pooled,
                           int* __restrict__ done,
                           const float* __restrict__ Wfcf, const float* __restrict__ bfcf,
                           const void* __restrict__ x, void* __restrict__ out,
                           int n, int nbrows, int gblocks) {
    __shared__ float red[8][128];
    int t = threadIdx.x;
    int chunk = (nbrows + gblocks - 1) / gblocks;
    int r0 = blockIdx.x * chunk;
    int r1 = r0 + chunk;
    if (r1 > nbrows) r1 = nbrows;

    float4 acc = {0.f, 0.f, 0.f, 0.f};
    const float4* p4 = (const float4*)partial;
    for (int i = r0 * 32 + t; i < r1 * 32; i += 256) {
        float4 v = p4[i];
        acc.x += v.x; acc.y += v.y; acc.z += v.z; acc.w += v.w;
    }
    int g = t >> 5;
    int fb = (t & 31) * 4;
    red[g][fb]     = acc.x;
    red[g][fb + 1] = acc.y;
    red[g][fb + 2] = acc.z;
    red[g][fb + 3] = acc.w;
    __syncthreads();
    if (t < 128) {
        float s = red[0][t] + red[1][t] + red[2][t] + red[3][t]
                + red[4][t] + red[5][t] + red[6][t] + red[7][t];
        atomicAdd(&pooled[t], s);
    }
    __threadfence();
    __shared__ int lastf;
    if (t == 0) lastf = (atomicAdd(done, 1) == gblocks - 1) ? 1 : 0;
    __syncthreads();
    if (!lastf) return;

    __shared__ int hits;
    __shared__ float pv[128];
    if (t == 0) hits = 0;
    __syncthreads();
    unsigned ew = (((const uint32_t*)x)[t] >> 7) & 0xFFu;
    unsigned long long bl = __ballot(ew >= 0x60u && ew <= 0x90u);
    if ((t & 63) == 0) atomicAdd(&hits, (int)__popcll(bl));
    if (t < 128)
        pv[t] = __hip_atomic_load(&pooled[t], __ATOMIC_RELAXED,
                                  __HIP_MEMORY_SCOPE_AGENT);
    __syncthreads();
    int isbf = (2 * hits > 256);
    if (t < 32) {
        float s = 0.f;
        for (int c = 0; c < 128; ++c) s += pv[c] * Wfcf[c * 32 + t];
        s = s * (1.0f / (float)n) + bfcf[t];
        if (isbf) ((unsigned short*)out)[t] = f2bf(s);
        else      ((float*)out)[t] = s;
    }
}

// ---- Launch -------------------------------------------------------------

extern "C" void kernel_launch(void* const* d_in, const int* in_sizes, int n_in,
                              void* d_out, int out_size, void* d_ws, size_t ws_size,
                              hipStream_t stream) {
    const void* x   = d_in[0];
    const int*  ei  = (const int*)d_in[1];
    const void* W1  = d_in[2];
    const void* b1  = d_in[3];
    const void* W2  = d_in[4];
    const void* b2  = d_in[5];
    const void* Wfc = d_in[6];
    const void* bfc = d_in[7];

    const int n = in_sizes[0] / FEAT;    // 50000
    const int E = in_sizes[1] / 2;       // 800000
    const int m = n * FEAT;              // 6.4M
    const int nagg = (n + 3) / 4;        // 12500
    const int psz  = (n + 7) / 8;        // 6250
    const int nscan = (n + 255) / 256;   // 196

    char* ws = (char*)d_ws;
    uint32_t*       hs8     = (uint32_t*)(ws);                     // 6.4MB used (12.8 reserved)
    unsigned short* xh      = (unsigned short*)(ws + 12800000);    // 12,800,000 (x hi / act1)
    unsigned short* xl      = (unsigned short*)(ws + 25600000);    // 12,800,000 (x lo / partials)
    int*            col     = (int*)(ws + 38400000);               // 3,200,000
    int2*           ebuf    = (int2*)(ws + 41600000);              // 12,800,000
    int*            deg     = (int*)(ws + 54400000);               // 200,000
    int*            row_ptr = (int*)(ws + 54600000);               // 200,016
    int*            cursor  = (int*)(ws + 54800016);               // 200,000
    float*          dinv    = (float*)(ws + 55000016);             // 200,000
    unsigned short* Wth1    = (unsigned short*)(ws + 55200016);    // 32,768
    unsigned short* Wtl1    = (unsigned short*)(ws + 55232784);    // 32,768
    unsigned short* Wth2    = (unsigned short*)(ws + 55265552);    // 32,768
    unsigned short* Wtl2    = (unsigned short*)(ws + 55298320);    // 32,768
    float*          b1f     = (float*)(ws + 55331088);             // 512
    float*          b2f     = (float*)(ws + 55331600);             // 512
    float*          Wfcf    = (float*)(ws + 55332112);             // 16,384
    float*          bfcf    = (float*)(ws + 55348496);             // 128
    // small zero region (one memset): pooled | bcnt | done | pad | bsum/boff
    float*          pooled  = (float*)(ws + 55348624);             // 512
    int*            bcnt    = (int*)(ws + 55349136);               // 32
    int*            done    = (int*)(ws + 55349168);               // 4 (+12 pad)
    int*            bsum    = (int*)(ws + 55349184);               // 784
    int*            boff    = (int*)(ws + 55349968);               // 784

    if (ws_size < 55350752) return;  // diagnostic: zero output => ws too small

    hipMemsetAsync(pooled, 0, 512 + 32 + 16 + 1568, stream);

    // 1) decode+bucket edges
    k_econv<<<(E + ECH - 1) / ECH, 256, 0, stream>>>(ei, ebuf, bcnt, E, n, psz);
    // 2) split x + zero deg
    k_split<<<(m / 8 + 255) / 256, 256, 0, stream>>>(x, m / 8, n, deg,
                                                     (u16x8*)xh, (u16x8*)xl);
    // 3) degree count
    k_degp<<<512, 256, 0, stream>>>(ebuf, bcnt, deg);
    // 4) 3-phase scan
    k_bsum<<<nscan, 256, 0, stream>>>(deg, bsum, dinv, n);
    k_bscan<<<1, 256, 0, stream>>>(bsum, boff, row_ptr, nscan, n);
    k_bapply<<<nscan, 256, 0, stream>>>(deg, boff, row_ptr, cursor, n);
    // 5) scatter
    k_scatp<<<512, 256, 0, stream>>>(ebuf, bcnt, cursor, col, E);
    // 6) weight prep
    k_wprep<<<146, 256, 0, stream>>>(W1, W2, b1, b2, Wfc, bfc,
                                     Wth1, Wtl1, Wth2, Wtl2,
                                     b1f, b2f, Wfcf, bfcf);

    int gemm_grid = (n + 15) / 16;
    // layer 1
    k_gemm<<<gemm_grid, 64, 0, stream>>>(xh, xl, Wth1, Wtl1, dinv, hs8, n, 1);
    k_agg<<<nagg, 256, 0, stream>>>((const unsigned short*)hs8, row_ptr, col, dinv,
                                    b1f, (uint32_t*)xh, nullptr, n, E);
    // layer 2 (act1 in xh; partials into xl region)
    float* partial = (float*)xl;
    k_gemm<<<gemm_grid, 64, 0, stream>>>(xh, nullptr, Wth2, Wtl2, dinv, hs8, n, 0);
    k_agg<<<nagg, 256, 0, stream>>>((const unsigned short*)hs8, row_ptr, col, dinv,
                                    b2f, nullptr, partial, n, E);
    // fused pooled-reduce + FC
    k_redfinal<<<100, 256, 0, stream>>>(partial, pooled, done, Wfcf, bfcf,
                                        x, d_out, n, nagg, 100);
}

// Round 10
// 323.181 us; speedup vs baseline: 1.1480x; 1.0171x over previous
//
#include <hip/hip_runtime.h>
#include <stdint.h>

#define FEAT 128
#define ECH 2048   // edges per econv block
#define CAP 200000 // per-partition edge capacity

typedef short bf16x8 __attribute__((ext_vector_type(8)));
typedef float f32x4 __attribute__((ext_vector_type(4)));
typedef float f32x2 __attribute__((ext_vector_type(2)));

__device__ __forceinline__ float bfs(unsigned short u) {
    uint32_t t = ((uint32_t)u) << 16;
    return __builtin_bit_cast(float, t);
}
__device__ __forceinline__ unsigned short f2bf(float f) {
    uint32_t u = __builtin_bit_cast(uint32_t, f);
    u += 0x7fffu + ((u >> 16) & 1u);
    return (unsigned short)(u >> 16);
}

// ---- fused prep: econv blocks [0,NE) + wprep blocks [NE,NE+146) ---------
__launch_bounds__(256)
__global__ void k_prep(const int* __restrict__ ei, int2* __restrict__ ebuf,
                       int* __restrict__ bcnt, int* __restrict__ deg,
                       int E, int n, int psz, int NE,
                       const void* W1, const void* W2,
                       const void* b1, const void* b2,
                       const void* Wfc, const void* bfc,
                       unsigned short* Wth1, unsigned short* Wtl1,
                       unsigned short* Wth2, unsigned short* Wtl2,
                       float* b1f, float* b2f, float* Wfcf, float* bfcf) {
    __shared__ int lflag;
    __shared__ int cnt[8], lofs[8], gbase[8];
    __shared__ int2 stage[ECH];
    __shared__ char sb[ECH];
    int t = threadIdx.x;

    if ((int)blockIdx.x >= NE) {
        // ---- wprep part ----
        __shared__ int hits;
        int blk = blockIdx.x - NE;
        const uint32_t* samp = (const uint32_t*)(blk < 64 ? W1 : (blk < 128 ? W2 : Wfc));
        if (t == 0) hits = 0;
        __syncthreads();
        unsigned ew = (samp[t] >> 7) & 0xFFu;
        unsigned long long bl = __ballot(ew >= 0x60u && ew <= 0x90u);
        if ((t & 63) == 0) atomicAdd(&hits, (int)__popcll(bl));
        __syncthreads();
        int isbf = (2 * hits > 256);
        if (blk < 128) {
            const void* W = (blk < 64) ? W1 : W2;
            unsigned short* th = (blk < 64) ? Wth1 : Wth2;
            unsigned short* tl = (blk < 64) ? Wtl1 : Wtl2;
            int idx = (blk & 63) * 256 + t;
            int nn = idx >> 7, k = idx & 127;
            int si = k * 128 + nn;
            float f = isbf ? bfs(((const unsigned short*)W)[si])
                           : ((const float*)W)[si];
            unsigned short h = f2bf(f);
            th[nn * 128 + k] = h;
            tl[nn * 128 + k] = f2bf(f - bfs(h));
        } else {
            int i = (blk - 128) * 256 + t;
            if (i >= 4384) return;
            const void* src; float* dst; int off;
            if (i < 128)       { src = b1;  dst = b1f;  off = i; }
            else if (i < 256)  { src = b2;  dst = b2f;  off = i - 128; }
            else if (i < 4352) { src = Wfc; dst = Wfcf; off = i - 256; }
            else               { src = bfc; dst = bfcf; off = i - 4352; }
            dst[off] = isbf ? bfs(((const unsigned short*)src)[off])
                            : ((const float*)src)[off];
        }
        return;
    }

    // ---- econv part (+ zero its deg slice) ----
    if (t < 128) {
        int di = blockIdx.x * 128 + t;
        if (di < n) deg[di] = 0;
    }
    if (t == 0) lflag = 0;
    if (t < 8) cnt[t] = 0;
    __syncthreads();
    if (ei[1 + 2 * t] != 0) atomicOr(&lflag, 1);   // odd words: 0 => int64
    __syncthreads();
    int is32 = lflag;

    int base = blockIdx.x * ECH;
    int s[8], d[8], p[8], slot[8];
    #pragma unroll
    for (int j = 0; j < 8; j++) {
        int e = base + j * 256 + t;
        int ss = 0, dd = 0;
        if (e < E) {
            ss = is32 ? ei[e]     : ei[2 * e];
            dd = is32 ? ei[E + e] : ei[2 * E + 2 * e];
            if ((unsigned)ss >= (unsigned)n) ss = 0;
            if ((unsigned)dd >= (unsigned)n) dd = 0;
            int pp = dd / psz;
            if (pp > 7) pp = 7;
            p[j] = pp;
            slot[j] = atomicAdd(&cnt[pp], 1);
        } else p[j] = -1;
        s[j] = ss; d[j] = dd;
    }
    __syncthreads();
    if (t == 0) {
        int acc = 0;
        #pragma unroll
        for (int i = 0; i < 8; i++) { lofs[i] = acc; acc += cnt[i]; }
    }
    __syncthreads();
    if (t < 8) gbase[t] = atomicAdd(&bcnt[t], cnt[t]);
    __syncthreads();
    #pragma unroll
    for (int j = 0; j < 8; j++) {
        if (p[j] >= 0) {
            int pos = lofs[p[j]] + slot[j];
            stage[pos] = make_int2(s[j], d[j]);
            sb[pos] = (char)p[j];
        }
    }
    __syncthreads();
    int tot = lofs[7] + cnt[7];
    for (int i = t; i < tot; i += 256) {
        int pp = sb[i];
        int off = gbase[pp] + (i - lofs[pp]);
        if (off < CAP) ebuf[(size_t)pp * CAP + off] = stage[i];
    }
}

// ---- partitioned degree count (bucketed edges, single pass) -------------
__launch_bounds__(256)
__global__ void k_degp(const int2* __restrict__ ebuf, const int* __restrict__ bcnt,
                       int* __restrict__ deg) {
    int p = blockIdx.x & 7;
    int nb = gridDim.x >> 3;
    int cnt = bcnt[p]; if (cnt > CAP) cnt = CAP;
    const int2* eb = ebuf + (size_t)p * CAP;
    for (int i = (blockIdx.x >> 3) * 256 + threadIdx.x; i < cnt; i += nb * 256)
        atomicAdd(&deg[eb[i].y], 1);
}

// ---- block sums (+ fused dinv) ------------------------------------------
__global__ void k_bsum(const int* __restrict__ deg, int* __restrict__ bsum,
                       float* __restrict__ dinv, int n) {
    __shared__ int ws[4];
    int t = threadIdx.x, lane = t & 63, w = t >> 6;
    int idx = blockIdx.x * 256 + t;
    int v = (idx < n) ? deg[idx] : 0;
    if (idx < n) dinv[idx] = rsqrtf((float)(v + 1));  // +1 self-loop
    int r = v;
    #pragma unroll
    for (int off = 32; off > 0; off >>= 1) r += __shfl_down(r, off, 64);
    if (lane == 0) ws[w] = r;
    __syncthreads();
    if (t == 0) bsum[blockIdx.x] = ws[0] + ws[1] + ws[2] + ws[3];
}

// ---- apply with self-computed block offset (replaces bscan+bapply) ------
__launch_bounds__(256)
__global__ void k_bapply2(const int* __restrict__ deg, const int* __restrict__ bsum,
                          int* __restrict__ row_ptr, int* __restrict__ cursor,
                          int n, int nb) {
    __shared__ int wred[4];
    __shared__ int wsum[4];
    __shared__ int boffs;
    int b = blockIdx.x, t = threadIdx.x, lane = t & 63, w = t >> 6;

    // prefix = sum of bsum[0..b-1]
    int pv = (t < b && t < nb) ? bsum[t] : 0;
    #pragma unroll
    for (int off = 32; off > 0; off >>= 1) pv += __shfl_down(pv, off, 64);
    if (lane == 0) wred[w] = pv;
    __syncthreads();
    if (t == 0) boffs = wred[0] + wred[1] + wred[2] + wred[3];
    __syncthreads();

    int idx = b * 256 + t;
    int v = (idx < n) ? deg[idx] : 0;
    int s = v;
    #pragma unroll
    for (int off = 1; off < 64; off <<= 1) {
        int x = __shfl_up(s, off, 64);
        if (lane >= off) s += x;
    }
    if (lane == 63) wsum[w] = s;
    __syncthreads();
    if (t == 0) {
        int acc = 0;
        #pragma unroll
        for (int i = 0; i < 4; i++) { int x = wsum[i]; wsum[i] = acc; acc += x; }
    }
    __syncthreads();
    int ex = boffs + s - v + wsum[w];
    if (idx < n) {
        row_ptr[idx] = ex;
        cursor[idx]  = ex;
    }
    if (idx == n - 1) row_ptr[n] = ex + v;
}

// ---- partitioned scatter (bucketed edges, single pass) ------------------
__launch_bounds__(256)
__global__ void k_scatp(const int2* __restrict__ ebuf, const int* __restrict__ bcnt,
                        int* __restrict__ cursor, int* __restrict__ col, int E) {
    int p = blockIdx.x & 7;
    int nb = gridDim.x >> 3;
    int cnt = bcnt[p]; if (cnt > CAP) cnt = CAP;
    const int2* eb = ebuf + (size_t)p * CAP;
    for (int i = (blockIdx.x >> 3) * 256 + threadIdx.x; i < cnt; i += nb * 256) {
        int2 e = eb[i];
        int pos = atomicAdd(&cursor[e.y], 1);
        if ((unsigned)pos < (unsigned)E) col[pos] = e.x;
    }
}

// ---- GEMM: hs_fp8 = fp8(dinv[row] * (X @ W)) ----------------------------
// fmt 0: X = raw input (f32 or bf16, per-wave sample); fmt 1: X = bf16 act.
// 256 threads = 4 waves, each owning one 16-row tile.
__launch_bounds__(256)
__global__ void k_gemm(const void* __restrict__ X,
                       const unsigned short* __restrict__ Wth,
                       const unsigned short* __restrict__ Wtl,
                       const float* __restrict__ dinv,
                       uint32_t* __restrict__ hs8, int n, int fmt) {
    __shared__ unsigned char lds8[4][16 * 128];
    int wave = threadIdx.x >> 6;
    int l = threadIdx.x & 63;
    int quad = l >> 4;
    int m16 = l & 15;
    int r0 = (blockIdx.x * 4 + wave) * 16;

    int isbf;
    if (fmt == 1) isbf = 1;
    else {
        unsigned ew = (((const uint32_t*)X)[l] >> 7) & 0xFFu;
        unsigned long long bl = __ballot(ew >= 0x60u && ew <= 0x90u);
        isbf = ((int)__popcll(bl) * 2 > 64) ? 1 : 0;
    }

    int ra = r0 + m16;
    if (ra > n - 1) ra = n - 1;
    bf16x8 ah[4], al[4];
    if (isbf) {
        const int4* Xv = (const int4*)X;
        #pragma unroll
        for (int kt = 0; kt < 4; kt++)
            ah[kt] = __builtin_bit_cast(bf16x8, Xv[ra * 16 + kt * 4 + quad]);
    } else {
        const float4* Xf = (const float4*)X;
        #pragma unroll
        for (int kt = 0; kt < 4; kt++) {
            int jj = kt * 4 + quad;
            float4 fa = Xf[ra * 32 + jj * 2];
            float4 fb = Xf[ra * 32 + jj * 2 + 1];
            float v[8] = {fa.x, fa.y, fa.z, fa.w, fb.x, fb.y, fb.z, fb.w};
            bf16x8 h, lo;
            #pragma unroll
            for (int j = 0; j < 8; j++) {
                unsigned short hh = f2bf(v[j]);
                h[j] = (short)hh;
                lo[j] = (short)f2bf(v[j] - bfs(hh));
            }
            ah[kt] = h;
            al[kt] = lo;
        }
    }

    float dv[4];
    #pragma unroll
    for (int reg = 0; reg < 4; reg++) {
        int row = r0 + quad * 4 + reg;
        if (row > n - 1) row = n - 1;
        dv[reg] = dinv[row];
    }

    const int4* Wvh = (const int4*)Wth;
    const int4* Wvl = (const int4*)Wtl;
    #pragma unroll
    for (int nt = 0; nt < 8; nt++) {
        f32x4 acc = {0.f, 0.f, 0.f, 0.f};
        int brow = (nt * 16 + m16) * 16;
        #pragma unroll
        for (int kt = 0; kt < 4; kt++) {
            bf16x8 bh = __builtin_bit_cast(bf16x8, Wvh[brow + kt * 4 + quad]);
            bf16x8 bl = __builtin_bit_cast(bf16x8, Wvl[brow + kt * 4 + quad]);
            acc = __builtin_amdgcn_mfma_f32_16x16x32_bf16(ah[kt], bh, acc, 0, 0, 0);
            acc = __builtin_amdgcn_mfma_f32_16x16x32_bf16(ah[kt], bl, acc, 0, 0, 0);
            if (!isbf)
                acc = __builtin_amdgcn_mfma_f32_16x16x32_bf16(al[kt], bh, acc, 0, 0, 0);
        }
        #pragma unroll
        for (int reg = 0; reg < 4; reg++) {
            float v = acc[reg] * dv[reg];
            int pk = __builtin_amdgcn_cvt_pk_fp8_f32(v, v, 0, false);
            lds8[wave][(quad * 4 + reg) * 128 + nt * 16 + m16] = (unsigned char)(pk & 0xFF);
        }
    }
    __syncthreads();
    const uint32_t* l32 = (const uint32_t*)lds8[wave];
    #pragma unroll
    for (int i = 0; i < 8; i++) {
        int idx = i * 64 + l;          // 0..511 within wave tile
        int row = idx >> 5;            // 0..15
        int grow = r0 + row;
        if (grow < n) hs8[grow * 32 + (idx & 31)] = l32[idx];
    }
}

// ---- Pull aggregation (fp8 hs): act = relu(dinv*(hs[d]+sum hs[s]) + b) --
__launch_bounds__(256)
__global__ void k_agg(const unsigned short* __restrict__ hsv,
                      const int* __restrict__ row_ptr,
                      const int* __restrict__ col, const float* __restrict__ dinv,
                      const float* __restrict__ bias,
                      uint32_t* __restrict__ outh, float* __restrict__ partial,
                      int n, int E) {
    __shared__ float pl[4][128];
    int wave = threadIdx.x >> 6;
    int lane = threadIdx.x & 63;
    int node = blockIdx.x * 4 + wave;
    bool active = (node < n);
    int nd = active ? node : 0;

    f32x2 sf = __builtin_amdgcn_cvt_pk_f32_fp8((int)hsv[nd * 64 + lane], false);
    float a0 = sf.x, a1 = sf.y;

    int e = row_ptr[nd];
    int end = active ? row_ptr[nd + 1] : e;
    if (e < 0) e = 0;
    if (end > E) end = E;

    for (; e + 8 <= end; e += 8) {
        unsigned s0 = (unsigned)col[e],     s1 = (unsigned)col[e + 1];
        unsigned s2 = (unsigned)col[e + 2], s3 = (unsigned)col[e + 3];
        unsigned s4 = (unsigned)col[e + 4], s5 = (unsigned)col[e + 5];
        unsigned s6 = (unsigned)col[e + 6], s7 = (unsigned)col[e + 7];
        if (s0 >= (unsigned)n) s0 = 0;
        if (s1 >= (unsigned)n) s1 = 0;
        if (s2 >= (unsigned)n) s2 = 0;
        if (s3 >= (unsigned)n) s3 = 0;
        if (s4 >= (unsigned)n) s4 = 0;
        if (s5 >= (unsigned)n) s5 = 0;
        if (s6 >= (unsigned)n) s6 = 0;
        if (s7 >= (unsigned)n) s7 = 0;
        int u0 = hsv[s0 * 64 + lane];
        int u1 = hsv[s1 * 64 + lane];
        int u2 = hsv[s2 * 64 + lane];
        int u3 = hsv[s3 * 64 + lane];
        int u4 = hsv[s4 * 64 + lane];
        int u5 = hsv[s5 * 64 + lane];
        int u6 = hsv[s6 * 64 + lane];
        int u7 = hsv[s7 * 64 + lane];
        f32x2 f0 = __builtin_amdgcn_cvt_pk_f32_fp8(u0, false);
        f32x2 f1 = __builtin_amdgcn_cvt_pk_f32_fp8(u1, false);
        f32x2 f2 = __builtin_amdgcn_cvt_pk_f32_fp8(u2, false);
        f32x2 f3 = __builtin_amdgcn_cvt_pk_f32_fp8(u3, false);
        f32x2 f4 = __builtin_amdgcn_cvt_pk_f32_fp8(u4, false);
        f32x2 f5 = __builtin_amdgcn_cvt_pk_f32_fp8(u5, false);
        f32x2 f6 = __builtin_amdgcn_cvt_pk_f32_fp8(u6, false);
        f32x2 f7 = __builtin_amdgcn_cvt_pk_f32_fp8(u7, false);
        a0 += f0.x + f1.x + f2.x + f3.x + f4.x + f5.x + f6.x + f7.x;
        a1 += f0.y + f1.y + f2.y + f3.y + f4.y + f5.y + f6.y + f7.y;
    }
    for (; e < end; ++e) {
        unsigned s0 = (unsigned)col[e];
        if (s0 >= (unsigned)n) s0 = 0;
        f32x2 f = __builtin_amdgcn_cvt_pk_f32_fp8((int)hsv[s0 * 64 + lane], false);
        a0 += f.x;
        a1 += f.y;
    }

    float dv = dinv[nd];
    float2 bu = ((const float2*)bias)[lane];
    float r0 = fmaxf(dv * a0 + bu.x, 0.f);
    float r1 = fmaxf(dv * a1 + bu.y, 0.f);
    if (!active) { r0 = 0.f; r1 = 0.f; }

    if (outh != nullptr && active) {
        outh[node * 64 + lane] = (uint32_t)f2bf(r0) | ((uint32_t)f2bf(r1) << 16);
    }
    if (partial != nullptr) {
        pl[wave][2 * lane]     = r0;
        pl[wave][2 * lane + 1] = r1;
        __syncthreads();
        int t = threadIdx.x;
        if (t < 128) {
            float ps = pl[0][t] + pl[1][t] + pl[2][t] + pl[3][t];
            partial[blockIdx.x * 128 + t] = ps;
        }
    }
}

// ---- fused pooled reduce + FC (last-block pattern) ----------------------
__launch_bounds__(256)
__global__ void k_redfinal(const float* __restrict__ partial, float* __restrict__ pooled,
                           int* __restrict__ done,
                           const float* __restrict__ Wfcf, const float* __restrict__ bfcf,
                           const void* __restrict__ x, void* __restrict__ out,
                           int n, int nbrows, int gblocks) {
    __shared__ float red[8][128];
    int t = threadIdx.x;
    int chunk = (nbrows + gblocks - 1) / gblocks;
    int r0 = blockIdx.x * chunk;
    int r1 = r0 + chunk;
    if (r1 > nbrows) r1 = nbrows;

    float4 acc = {0.f, 0.f, 0.f, 0.f};
    const float4* p4 = (const float4*)partial;
    for (int i = r0 * 32 + t; i < r1 * 32; i += 256) {
        float4 v = p4[i];
        acc.x += v.x; acc.y += v.y; acc.z += v.z; acc.w += v.w;
    }
    int g = t >> 5;
    int fb = (t & 31) * 4;
    red[g][fb]     = acc.x;
    red[g][fb + 1] = acc.y;
    red[g][fb + 2] = acc.z;
    red[g][fb + 3] = acc.w;
    __syncthreads();
    if (t < 128) {
        float s = red[0][t] + red[1][t] + red[2][t] + red[3][t]
                + red[4][t] + red[5][t] + red[6][t] + red[7][t];
        atomicAdd(&pooled[t], s);
    }
    __threadfence();
    __shared__ int lastf;
    if (t == 0) lastf = (atomicAdd(done, 1) == gblocks - 1) ? 1 : 0;
    __syncthreads();
    if (!lastf) return;

    __shared__ int hits;
    __shared__ float pv[128];
    if (t == 0) hits = 0;
    __syncthreads();
    unsigned ew = (((const uint32_t*)x)[t] >> 7) & 0xFFu;
    unsigned long long bl = __ballot(ew >= 0x60u && ew <= 0x90u);
    if ((t & 63) == 0) atomicAdd(&hits, (int)__popcll(bl));
    if (t < 128)
        pv[t] = __hip_atomic_load(&pooled[t], __ATOMIC_RELAXED,
                                  __HIP_MEMORY_SCOPE_AGENT);
    __syncthreads();
    int isbf = (2 * hits > 256);
    if (t < 32) {
        float s = 0.f;
        for (int c = 0; c < 128; ++c) s += pv[c] * Wfcf[c * 32 + t];
        s = s * (1.0f / (float)n) + bfcf[t];
        if (isbf) ((unsigned short*)out)[t] = f2bf(s);
        else      ((float*)out)[t] = s;
    }
}

// ---- Launch -------------------------------------------------------------

extern "C" void kernel_launch(void* const* d_in, const int* in_sizes, int n_in,
                              void* d_out, int out_size, void* d_ws, size_t ws_size,
                              hipStream_t stream) {
    const void* x   = d_in[0];
    const int*  ei  = (const int*)d_in[1];
    const void* W1  = d_in[2];
    const void* b1  = d_in[3];
    const void* W2  = d_in[4];
    const void* b2  = d_in[5];
    const void* Wfc = d_in[6];
    const void* bfc = d_in[7];

    const int n = in_sizes[0] / FEAT;    // 50000
    const int E = in_sizes[1] / 2;       // 800000
    const int nagg = (n + 3) / 4;        // 12500
    const int psz  = (n + 7) / 8;        // 6250
    const int nscan = (n + 255) / 256;   // 196
    const int NE   = (E + ECH - 1) / ECH;// 391

    char* ws = (char*)d_ws;
    uint32_t*       hs8     = (uint32_t*)(ws);                     // 6.4MB used
    unsigned short* act     = (unsigned short*)(ws + 12800000);    // 12.8MB (act1 bf16)
    float*          partial = (float*)(ws + 25600000);             // 6.4MB used
    int*            col     = (int*)(ws + 38400000);               // 3.2MB
    int2*           ebuf    = (int2*)(ws + 41600000);              // 12.8MB
    int*            deg     = (int*)(ws + 54400000);               // 200,000
    int*            row_ptr = (int*)(ws + 54600000);               // 200,016
    int*            cursor  = (int*)(ws + 54800016);               // 200,000
    float*          dinv    = (float*)(ws + 55000016);             // 200,000
    unsigned short* Wth1    = (unsigned short*)(ws + 55200016);    // 32,768
    unsigned short* Wtl1    = (unsigned short*)(ws + 55232784);    // 32,768
    unsigned short* Wth2    = (unsigned short*)(ws + 55265552);    // 32,768
    unsigned short* Wtl2    = (unsigned short*)(ws + 55298320);    // 32,768
    float*          b1f     = (float*)(ws + 55331088);             // 512
    float*          b2f     = (float*)(ws + 55331600);             // 512
    float*          Wfcf    = (float*)(ws + 55332112);             // 16,384
    float*          bfcf    = (float*)(ws + 55348496);             // 128
    // small zero region: pooled | bcnt | done(+pad) | bsum
    float*          pooled  = (float*)(ws + 55348624);             // 512
    int*            bcnt    = (int*)(ws + 55349136);               // 32
    int*            done    = (int*)(ws + 55349168);               // 4 (+12 pad)
    int*            bsum    = (int*)(ws + 55349184);               // 784

    if (ws_size < 55350752) return;  // diagnostic: zero output => ws too small

    hipMemsetAsync(pooled, 0, 512 + 32 + 16 + 784, stream);

    // 1) fused prep: edge decode+bucket (+deg zero) | weight/bias prep
    k_prep<<<NE + 146, 256, 0, stream>>>(ei, ebuf, bcnt, deg, E, n, psz, NE,
                                         W1, W2, b1, b2, Wfc, bfc,
                                         Wth1, Wtl1, Wth2, Wtl2,
                                         b1f, b2f, Wfcf, bfcf);
    // 2) degree count
    k_degp<<<512, 256, 0, stream>>>(ebuf, bcnt, deg);
    // 3) scan (2 kernels)
    k_bsum<<<nscan, 256, 0, stream>>>(deg, bsum, dinv, n);
    k_bapply2<<<nscan, 256, 0, stream>>>(deg, bsum, row_ptr, cursor, n, nscan);
    // 4) scatter
    k_scatp<<<512, 256, 0, stream>>>(ebuf, bcnt, cursor, col, E);

    int gemm_grid = (n + 63) / 64;   // 4 tiles of 16 rows per block
    // layer 1 (reads x directly, f32/bf16 auto)
    k_gemm<<<gemm_grid, 256, 0, stream>>>(x, Wth1, Wtl1, dinv, hs8, n, 0);
    k_agg<<<nagg, 256, 0, stream>>>((const unsigned short*)hs8, row_ptr, col, dinv,
                                    b1f, (uint32_t*)act, nullptr, n, E);
    // layer 2 (act bf16)
    k_gemm<<<gemm_grid, 256, 0, stream>>>(act, Wth2, Wtl2, dinv, hs8, n, 1);
    k_agg<<<nagg, 256, 0, stream>>>((const unsigned short*)hs8, row_ptr, col, dinv,
                                    b2f, nullptr, partial, n, E);
    // fused pooled-reduce + FC
    k_redfinal<<<100, 256, 0, stream>>>(partial, pooled, done, Wfcf, bfcf,
                                        x, d_out, n, nagg, 100);
}